// Round 9
// baseline (456.034 us; speedup 1.0000x reference)
//
#include <hip/hip_runtime.h>

#define N_NODES 30000
#define N_EDGES 960000
#define NGRAPH  64
#define BN_EPS  1e-5f

typedef __bf16 bf16x8 __attribute__((ext_vector_type(8)));
typedef float  f32x4  __attribute__((ext_vector_type(4)));

__device__ __forceinline__ unsigned short f2bf(float f) {
  union { float f; unsigned u; } v; v.f = f;
  unsigned r = (v.u + 0x7FFFu + ((v.u >> 16) & 1u)) >> 16;
  return (unsigned short)r;
}
__device__ __forceinline__ float bf2f(unsigned short u) {
  union { unsigned u; float f; } v; v.u = ((unsigned)u) << 16;
  return v.f;
}
__device__ __forceinline__ float bflo(unsigned w) {
  union { unsigned u; float f; } v; v.u = w << 16; return v.f;
}
__device__ __forceinline__ float bfhi(unsigned w) {
  union { unsigned u; float f; } v; v.u = w & 0xFFFF0000u; return v.f;
}
__device__ __forceinline__ void gld_lds16(const void* g, void* l) {
  __builtin_amdgcn_global_load_lds(
      (const __attribute__((address_space(1))) unsigned int*)g,
      (__attribute__((address_space(3))) unsigned int*)l, 16, 0, 0);
}
__device__ __forceinline__ bf16x8 cvt_hi(const float* v) {
  bf16x8 h;
#pragma unroll
  for (int j = 0; j < 8; ++j) {
    unsigned short s = f2bf(v[j]);
    h[j] = *(__bf16*)&s;
  }
  return h;
}

// ---------------- prep: hist (938) + weight transpose-cast (36) + cnt (1) ----------------
__global__ void prep_kernel(const int* __restrict__ ei, int* __restrict__ deg,
                            const float* __restrict__ gw, const float* __restrict__ mw,
                            unsigned short* __restrict__ wth,
                            unsigned short* __restrict__ mwth, unsigned short* __restrict__ mwtl,
                            const int* __restrict__ batch, int* __restrict__ cnt) {
  __shared__ float T[64][65];
  int b = blockIdx.x;
  if (b < 938) {
    int i = (b * 256 + (int)threadIdx.x) * 4;
    if (i < N_EDGES) {
      int4 d = *(const int4*)(ei + N_EDGES + i);
      atomicAdd(&deg[d.x], 1); atomicAdd(&deg[d.y], 1);
      atomicAdd(&deg[d.z], 1); atomicAdd(&deg[d.w], 1);
    }
    return;
  }
  if (b == 974) {
    if (threadIdx.x < 64) {
      int g = threadIdx.x;
      int lo = 0, hi = N_NODES;
      while (lo < hi) { int mid = (lo + hi) >> 1; if (batch[mid] < g) lo = mid + 1; else hi = mid; }
      int start = lo;
      lo = 0; hi = N_NODES;
      while (lo < hi) { int mid = (lo + hi) >> 1; if (batch[mid] < g + 1) lo = mid + 1; else hi = mid; }
      cnt[g] = lo - start;
    }
    return;
  }
  int b2 = b - 938;   // 0..35
  const float* src; unsigned short *dh, *dl; int K, Nn, kt, nt;
  if (b2 < 28) { src = gw; dh = wth; dl = nullptr; K = 448; Nn = 256; kt = b2 >> 2; nt = b2 & 3; }
  else { int b3 = b2 - 28; src = mw; dh = mwth; dl = mwtl; K = 256; Nn = 128; kt = b3 >> 1; nt = b3 & 1; }
  int tid = threadIdx.x;
  int nl = tid & 63, kg = tid >> 6;
#pragma unroll
  for (int j = 0; j < 16; ++j) {
    int k = kt * 64 + kg * 16 + j;
    T[kg * 16 + j][nl] = src[(size_t)k * Nn + nt * 64 + nl];
  }
  __syncthreads();
#pragma unroll
  for (int j = 0; j < 16; ++j) {
    int n = nt * 64 + kg * 16 + j;
    float v = T[nl][kg * 16 + j];
    unsigned short h = f2bf(v);
    size_t o = (size_t)n * K + kt * 64 + nl;
    dh[o] = h;
    if (dl) dl[o] = f2bf(v - bf2f(h));
  }
}

__global__ void scan_kernel(const int* __restrict__ deg, int* __restrict__ offs,
                            int* __restrict__ cur, int n) {
  __shared__ int wsum[16], wpre[16];
  __shared__ int running;
  int tid = threadIdx.x, widx = tid >> 6, lane = tid & 63;
  if (tid == 0) running = 0;
  __syncthreads();
  for (int base = 0; base < n; base += 8192) {
    int i0 = base + tid * 8;
    int v[8];
#pragma unroll
    for (int j = 0; j < 8; ++j) { int i = i0 + j; v[j] = (i < n) ? deg[i] : 0; }
    int pre[8]; int t = 0;
#pragma unroll
    for (int j = 0; j < 8; ++j) { pre[j] = t; t += v[j]; }
    int s = t;
#pragma unroll
    for (int o = 1; o <= 32; o <<= 1) {
      int tt = __shfl_up(s, o, 64);
      if (lane >= o) s += tt;
    }
    if (lane == 63) wsum[widx] = s;
    __syncthreads();
    if (tid == 0) {
      int a = 0;
#pragma unroll
      for (int j = 0; j < 16; ++j) { wpre[j] = a; a += wsum[j]; }
    }
    __syncthreads();
    int boff = running + wpre[widx] + (s - t);
#pragma unroll
    for (int j = 0; j < 8; ++j) {
      int i = i0 + j;
      if (i < n) { int p = boff + pre[j]; offs[i] = p; cur[i] = p; }
    }
    __syncthreads();
    if (tid == 0) running += wpre[15] + wsum[15];
    __syncthreads();
  }
  if (tid == 0) offs[n] = running;
}

// standalone scatter (R8 lesson: fusing this latency-bound atomic kernel into the MFMA
// kernel halves the MFMA waves per CU — merged 94-102us vs split ~60+~22)
__global__ void scatter_kernel(const int* __restrict__ ei, int* __restrict__ cur,
                               int* __restrict__ csr) {
  int i = (blockIdx.x * 256 + threadIdx.x) * 4;
  if (i < N_EDGES) {
    int4 d = *(const int4*)(ei + N_EDGES + i);
    int4 sv = *(const int4*)(ei + i);
    int p0 = atomicAdd(&cur[d.x], 1); csr[p0] = sv.x;
    int p1 = atomicAdd(&cur[d.y], 1); csr[p1] = sv.y;
    int p2 = atomicAdd(&cur[d.z], 1); csr[p2] = sv.z;
    int p3 = atomicAdd(&cur[d.w], 1); csr[p3] = sv.w;
  }
}

// ---------------- GEMM1: A direct-to-registers, only B through LDS ----------------
// 938 blocks = 469 row-tiles x 2 col-halves (ch == head). Wave w = rows [w*16, w*16+16).
// A-frag = x[r0+w*16+m][k0+quad*8..+8] loaded straight from global (32B/lane), split-bf16
// in regs. LDS = 8KB B-hi panel only; 2 gld_lds + 16 MFMA per iter.
__global__ void __launch_bounds__(256) gat_gemm_kernel(
    const float* __restrict__ x,
    const unsigned short* __restrict__ wth,
    const float* __restrict__ asrc, const float* __restrict__ adst,
    unsigned short* __restrict__ xp, float* __restrict__ a_s, float* __restrict__ a_d) {
  __shared__ unsigned short Bh[4 * 128 * 8];   // 8KB, [q][n][8]
  int tid = threadIdx.x;
  int w = tid >> 6, lane = tid & 63;
  int m = lane & 15, quad = lane >> 4;
  int rt = blockIdx.x >> 1, ch = blockIdx.x & 1;
  int r0 = rt * 64;
  int arow = r0 + w * 16 + m;
  int arc = min(arow, N_NODES - 1);            // clamp: garbage rows never stored
  const float* ap = x + (size_t)arc * 448 + quad * 8;
  const unsigned short* bsh = wth + (size_t)(ch * 128) * 448;

  f32x4 acc[8];
#pragma unroll
  for (int c = 0; c < 8; ++c) acc[c] = (f32x4){0.f, 0.f, 0.f, 0.f};

  for (int kc = 0; kc < 14; ++kc) {
    int k0 = kc * 32;
    // stage B-hi: wave w stages k-subchunk q=w (2 x 1KB)
#pragma unroll
    for (int i = 0; i < 2; ++i)
      gld_lds16(bsh + (size_t)(i * 64 + lane) * 448 + k0 + w * 8, Bh + w * 1024 + i * 512);
    // A in regs: 8 consecutive fp32, split to bf16 hi/lo (independent of barrier)
    float av[8];
    *(float4*)(av) = *(const float4*)(ap + k0);
    *(float4*)(av + 4) = *(const float4*)(ap + k0 + 4);
    bf16x8 ah, al;
#pragma unroll
    for (int j = 0; j < 8; ++j) {
      unsigned short h = f2bf(av[j]);
      unsigned short l = f2bf(av[j] - bf2f(h));
      ah[j] = *(__bf16*)&h;
      al[j] = *(__bf16*)&l;
    }
    __syncthreads();
#pragma unroll
    for (int c = 0; c < 8; ++c) {
      bf16x8 bh = *(const bf16x8*)(Bh + quad * 1024 + (c * 16 + m) * 8);
      acc[c] = __builtin_amdgcn_mfma_f32_16x16x32_bf16(ah, bh, acc[c], 0, 0, 0);
      acc[c] = __builtin_amdgcn_mfma_f32_16x16x32_bf16(al, bh, acc[c], 0, 0, 0);
    }
    __syncthreads();
  }
  float ps[4] = {0, 0, 0, 0}, pd[4] = {0, 0, 0, 0};
#pragma unroll
  for (int c = 0; c < 8; ++c) {
    int col = ch * 128 + c * 16 + m;
    float sa = asrc[col], da = adst[col];
#pragma unroll
    for (int r = 0; r < 4; ++r) {
      float v = acc[c][r];
      ps[r] += v * sa; pd[r] += v * da;
    }
  }
#pragma unroll
  for (int o = 1; o <= 8; o <<= 1) {
#pragma unroll
    for (int r = 0; r < 4; ++r) {
      ps[r] += __shfl_xor(ps[r], o);
      pd[r] += __shfl_xor(pd[r], o);
    }
  }
  int rowb = r0 + w * 16 + quad * 4;
  if (m == 0) {
#pragma unroll
    for (int r = 0; r < 4; ++r) {
      int row = rowb + r;
      if (row < N_NODES) {
        a_s[2 * row + ch] = ps[r];
        a_d[2 * row + ch] = pd[r];
      }
    }
  }
#pragma unroll
  for (int r = 0; r < 4; ++r) {
    int row = rowb + r;
    if (row < N_NODES) {
#pragma unroll
      for (int c = 0; c < 8; ++c)
        xp[(size_t)row * 256 + ch * 128 + c * 16 + m] = f2bf(acc[c][r]);
    }
  }
}

// ---------------- attention: one wave per dst node; 16 edges/iter ----------------
__global__ void attn_kernel(const unsigned short* __restrict__ xp,
                            const float* __restrict__ a_s, const float* __restrict__ a_d,
                            const int* __restrict__ offs, const int* __restrict__ csr,
                            const float* __restrict__ bias, unsigned short* __restrict__ y) {
  int nid = (blockIdx.x * 256 + (int)threadIdx.x) >> 6;
  int lane = threadIdx.x & 63;
  int l32 = lane & 31;
  int grp = lane >> 5;
  int h2 = l32 >> 4;
  float d0 = a_d[2 * nid], d1 = a_d[2 * nid + 1];
  float s0 = a_s[2 * nid], s1 = a_s[2 * nid + 1];
  int beg = offs[nid], end = offs[nid + 1];
  int deg = end - beg;
  float e0s = s0 + d0; e0s = e0s > 0.f ? e0s : 0.2f * e0s;
  float e1s = s1 + d1; e1s = e1s > 0.f ? e1s : 0.2f * e1s;

  if (deg <= 64) {
    int sreg = nid;
    float p0 = 0.f, p1 = 0.f;
    float e0 = -1e30f, e1 = -1e30f;
    if (lane < deg) {
      sreg = csr[beg + lane];
      float as0 = a_s[2 * sreg], as1 = a_s[2 * sreg + 1];
      e0 = as0 + d0; e0 = e0 > 0.f ? e0 : 0.2f * e0;
      e1 = as1 + d1; e1 = e1 > 0.f ? e1 : 0.2f * e1;
    }
    float m0 = fmaxf(e0, e0s), m1 = fmaxf(e1, e1s);
#pragma unroll
    for (int o = 32; o; o >>= 1) {
      m0 = fmaxf(m0, __shfl_xor(m0, o));
      m1 = fmaxf(m1, __shfl_xor(m1, o));
    }
    if (lane < deg) { p0 = __expf(e0 - m0); p1 = __expf(e1 - m1); }
    float ws0 = p0, ws1 = p1;
#pragma unroll
    for (int o = 32; o; o >>= 1) { ws0 += __shfl_xor(ws0, o); ws1 += __shfl_xor(ws1, o); }
    float wself0 = __expf(e0s - m0), wself1 = __expf(e1s - m1);
    float inv = 1.f / (h2 ? (ws1 + wself1) : (ws0 + wself0));

    float acc[8] = {0.f, 0.f, 0.f, 0.f, 0.f, 0.f, 0.f, 0.f};
    const unsigned* xpw = (const unsigned*)xp;
    {
      float wgt = grp ? 0.f : (h2 ? wself1 : wself0);
      uint4 u = *(const uint4*)(xpw + (size_t)nid * 128 + l32 * 4);
      acc[0] += wgt * bflo(u.x); acc[1] += wgt * bfhi(u.x);
      acc[2] += wgt * bflo(u.y); acc[3] += wgt * bfhi(u.y);
      acc[4] += wgt * bflo(u.z); acc[5] += wgt * bfhi(u.z);
      acc[6] += wgt * bflo(u.w); acc[7] += wgt * bfhi(u.w);
    }
    for (int j0 = 0; j0 < deg; j0 += 16) {
      int si[8]; float g[8];
#pragma unroll
      for (int i = 0; i < 8; ++i) {
        int e = j0 + 2 * i + grp;
        si[i] = __shfl(sreg, e);
        float a0 = __shfl(p0, e), a1 = __shfl(p1, e);
        g[i] = h2 ? a1 : a0;
      }
      uint4 u[8];
#pragma unroll
      for (int i = 0; i < 8; ++i)
        u[i] = *(const uint4*)(xpw + (size_t)si[i] * 128 + l32 * 4);
#pragma unroll
      for (int i = 0; i < 8; ++i) {
        acc[0] += g[i] * bflo(u[i].x); acc[1] += g[i] * bfhi(u[i].x);
        acc[2] += g[i] * bflo(u[i].y); acc[3] += g[i] * bfhi(u[i].y);
        acc[4] += g[i] * bflo(u[i].z); acc[5] += g[i] * bfhi(u[i].z);
        acc[6] += g[i] * bflo(u[i].w); acc[7] += g[i] * bfhi(u[i].w);
      }
    }
#pragma unroll
    for (int i = 0; i < 8; ++i) acc[i] += __shfl_xor(acc[i], 32);
    if (grp == 0) {
      int c0 = l32 * 8;
      float4 b0 = *(const float4*)(bias + c0);
      float4 b1 = *(const float4*)(bias + c0 + 4);
      float ob[8] = {b0.x, b0.y, b0.z, b0.w, b1.x, b1.y, b1.z, b1.w};
      unsigned short h[8];
#pragma unroll
      for (int i = 0; i < 8; ++i) {
        float v = acc[i] * inv + ob[i];
        v = v > 0.f ? v : __expf(v) - 1.f;
        h[i] = f2bf(v);
      }
      uint4 o;
      o.x = (unsigned)h[0] | ((unsigned)h[1] << 16);
      o.y = (unsigned)h[2] | ((unsigned)h[3] << 16);
      o.z = (unsigned)h[4] | ((unsigned)h[5] << 16);
      o.w = (unsigned)h[6] | ((unsigned)h[7] << 16);
      *(uint4*)(y + (size_t)nid * 256 + c0) = o;
    }
    return;
  }

  // slow path (deg > 64)
  int head = lane >> 5;
  float m0 = e0s, m1 = e1s;
  for (int j = beg + lane; j < end; j += 64) {
    int s = csr[j];
    float as0 = a_s[2 * s], as1 = a_s[2 * s + 1];
    float e0 = as0 + d0; e0 = e0 > 0.f ? e0 : 0.2f * e0;
    float e1 = as1 + d1; e1 = e1 > 0.f ? e1 : 0.2f * e1;
    m0 = fmaxf(m0, e0); m1 = fmaxf(m1, e1);
  }
#pragma unroll
  for (int o = 32; o; o >>= 1) {
    m0 = fmaxf(m0, __shfl_xor(m0, o));
    m1 = fmaxf(m1, __shfl_xor(m1, o));
  }
  float dh = head ? d1 : d0;
  float mh = head ? m1 : m0;
  float ax, ay, az, aw, wsum;
  {
    float e = head ? e1s : e0s;
    float wgt = __expf(e - mh);
    ushort4 u = *(const ushort4*)(xp + (size_t)nid * 256 + lane * 4);
    ax = wgt * bf2f(u.x); ay = wgt * bf2f(u.y); az = wgt * bf2f(u.z); aw = wgt * bf2f(u.w);
    wsum = wgt;
  }
  for (int j = beg; j < end; ++j) {
    int s = csr[j];
    float as = a_s[2 * s + head];
    float e = as + dh; e = e > 0.f ? e : 0.2f * e;
    float wgt = __expf(e - mh);
    ushort4 u = *(const ushort4*)(xp + (size_t)s * 256 + lane * 4);
    ax += wgt * bf2f(u.x); ay += wgt * bf2f(u.y); az += wgt * bf2f(u.z); aw += wgt * bf2f(u.w);
    wsum += wgt;
  }
  float inv = 1.f / wsum;
  float4 b4 = *(const float4*)(bias + lane * 4);
  float o0 = ax * inv + b4.x, o1 = ay * inv + b4.y;
  float o2 = az * inv + b4.z, o3 = aw * inv + b4.w;
  o0 = o0 > 0.f ? o0 : __expf(o0) - 1.f;
  o1 = o1 > 0.f ? o1 : __expf(o1) - 1.f;
  o2 = o2 > 0.f ? o2 : __expf(o2) - 1.f;
  o3 = o3 > 0.f ? o3 : __expf(o3) - 1.f;
  ushort4 yo; yo.x = f2bf(o0); yo.y = f2bf(o1); yo.z = f2bf(o2); yo.w = f2bf(o3);
  *(ushort4*)(y + (size_t)nid * 256 + lane * 4) = yo;
}

// ---------------- GEMM2: A direct-from-global (y is bf16 already), B split via LDS ----------------
__global__ void __launch_bounds__(256) mlp_gemm_kernel(
    const unsigned short* __restrict__ y,
    const unsigned short* __restrict__ mwth, const unsigned short* __restrict__ mwtl,
    const float* __restrict__ mlp_b, const int* __restrict__ batch,
    float* __restrict__ S, float* __restrict__ Q) {
  __shared__ unsigned short Bh[4 * 128 * 8], Bl[4 * 128 * 8];   // 8KB + 8KB
  __shared__ float Sloc[128], Qloc[128];
  int tid = threadIdx.x;
  int w = tid >> 6, lane = tid & 63;
  int m = lane & 15, quad = lane >> 4;
  int r0 = blockIdx.x * 64;
  if (tid < 128) { Sloc[tid] = 0.f; Qloc[tid] = 0.f; }
  const unsigned short* ap = y + (size_t)(r0 + w * 16 + m) * 256 + quad * 8;

  f32x4 acc[8];
#pragma unroll
  for (int c = 0; c < 8; ++c) acc[c] = (f32x4){0.f, 0.f, 0.f, 0.f};

  for (int kc = 0; kc < 8; ++kc) {
    int k0 = kc * 32;
#pragma unroll
    for (int i = 0; i < 2; ++i) {
      int n = i * 64 + lane;
      gld_lds16(mwth + (size_t)n * 256 + k0 + w * 8, Bh + w * 1024 + i * 512);
      gld_lds16(mwtl + (size_t)n * 256 + k0 + w * 8, Bl + w * 1024 + i * 512);
    }
    bf16x8 ah = *(const bf16x8*)(ap + k0);
    __syncthreads();
#pragma unroll
    for (int c = 0; c < 8; ++c) {
      bf16x8 bh = *(const bf16x8*)(Bh + quad * 1024 + (c * 16 + m) * 8);
      bf16x8 bl = *(const bf16x8*)(Bl + quad * 1024 + (c * 16 + m) * 8);
      acc[c] = __builtin_amdgcn_mfma_f32_16x16x32_bf16(ah, bh, acc[c], 0, 0, 0);
      acc[c] = __builtin_amdgcn_mfma_f32_16x16x32_bf16(ah, bl, acc[c], 0, 0, 0);
    }
    __syncthreads();
  }
  int rowb = r0 + w * 16 + quad * 4;
  int gfirst = batch[r0];
  int glast = batch[min(r0 + 63, N_NODES - 1)];
  bool uni = (gfirst == glast);
  bool valid[4]; int gg[4];
#pragma unroll
  for (int r = 0; r < 4; ++r) {
    int row = rowb + r;
    valid[r] = row < N_NODES;
    gg[r] = (!uni && valid[r]) ? batch[row] : gfirst;
  }
#pragma unroll
  for (int c = 0; c < 8; ++c) {
    int col = c * 16 + m;
    float bv = mlp_b[col];
    float sc = 0.f, qc = 0.f;
#pragma unroll
    for (int r = 0; r < 4; ++r) {
      if (valid[r]) {
        float v = acc[c][r] + bv;
        qc += v * v;
        if (uni) sc += v;
        else atomicAdd(&S[gg[r] * 128 + col], v);
      }
    }
    qc += __shfl_xor(qc, 16); qc += __shfl_xor(qc, 32);
    sc += __shfl_xor(sc, 16); sc += __shfl_xor(sc, 32);
    if (quad == 0) {
      atomicAdd(&Qloc[col], qc);
      if (uni) atomicAdd(&Sloc[col], sc);
    }
  }
  __syncthreads();
  if (tid < 128) {
    atomicAdd(&Q[tid], Qloc[tid]);
    if (uni) atomicAdd(&S[gfirst * 128 + tid], Sloc[tid]);
  }
}

// ---------------- FC head ----------------
__global__ void fc1_kernel(const float* __restrict__ S, const float* __restrict__ Q,
                           const int* __restrict__ cnt, const float* __restrict__ g0,
                           const float* __restrict__ b0,
                           const float* __restrict__ w, const float* __restrict__ b,
                           const float* __restrict__ bng, const float* __restrict__ bnb,
                           float* __restrict__ z1t) {
  __shared__ float hp[64 * 129];
  int tid = threadIdx.x;
  if (tid < 128) {
    int c = tid;
    float sum = 0.f;
    for (int g = 0; g < NGRAPH; ++g) sum += S[g * 128 + c];
    float mu = sum / (float)N_NODES;
    float var = Q[c] / (float)N_NODES - mu * mu;
    float gam = g0[c] * rsqrtf(var + BN_EPS);
    float bet = b0[c];
    for (int g = 0; g < NGRAPH; ++g) {
      float k = (float)cnt[g];
      hp[g * 129 + c] = gam * (S[g * 128 + c] - k * mu) + k * bet;
    }
  }
  __syncthreads();
  int wv = tid >> 6, lane = tid & 63;
  int j = blockIdx.x * 4 + wv;
  float acc = b[j];
  for (int c = 0; c < 128; ++c) acc += hp[lane * 129 + c] * w[c * 512 + j];
  float s1 = acc, s2 = acc * acc;
#pragma unroll
  for (int o = 32; o; o >>= 1) { s1 += __shfl_xor(s1, o); s2 += __shfl_xor(s2, o); }
  float mu = s1 * (1.f / 64.f), var = s2 * (1.f / 64.f) - mu * mu;
  float z = bng[j] * (acc - mu) * rsqrtf(var + BN_EPS) + bnb[j];
  z1t[j * 64 + lane] = fmaxf(z, 0.f);
}

__global__ void fc2_kernel(const float* __restrict__ z1t, const float* __restrict__ w,
                           const float* __restrict__ b, const float* __restrict__ bng,
                           const float* __restrict__ bnb, float* __restrict__ z2t) {
  int wv = threadIdx.x >> 6, lane = threadIdx.x & 63;
  int j = blockIdx.x * 4 + wv;
  float acc = b[j];
  for (int c = 0; c < 512; ++c) acc += z1t[c * 64 + lane] * w[c * 256 + j];
  float s1 = acc, s2 = acc * acc;
#pragma unroll
  for (int o = 32; o; o >>= 1) { s1 += __shfl_xor(s1, o); s2 += __shfl_xor(s2, o); }
  float mu = s1 * (1.f / 64.f), var = s2 * (1.f / 64.f) - mu * mu;
  float z = bng[j] * (acc - mu) * rsqrtf(var + BN_EPS) + bnb[j];
  z2t[j * 64 + lane] = fmaxf(z, 0.f);
}

__global__ void fc3_kernel(const float* __restrict__ z2t, const float* __restrict__ w,
                           const float* __restrict__ b, const float* __restrict__ bng,
                           const float* __restrict__ bnb, float* __restrict__ out) {
  int lane = threadIdx.x;
  float acc = b[0];
  for (int c = 0; c < 256; ++c) acc += z2t[c * 64 + lane] * w[c];
  float s1 = acc, s2 = acc * acc;
#pragma unroll
  for (int o = 32; o; o >>= 1) { s1 += __shfl_xor(s1, o); s2 += __shfl_xor(s2, o); }
  float mu = s1 * (1.f / 64.f), var = s2 * (1.f / 64.f) - mu * mu;
  out[lane] = bng[0] * (acc - mu) * rsqrtf(var + BN_EPS) + bnb[0];
}

extern "C" void kernel_launch(void* const* d_in, const int* in_sizes, int n_in,
                              void* d_out, int out_size, void* d_ws, size_t ws_size,
                              hipStream_t stream) {
  const float* x     = (const float*)d_in[0];
  const float* gat_w = (const float*)d_in[1];
  const float* a_src = (const float*)d_in[2];
  const float* a_dst = (const float*)d_in[3];
  const float* gbias = (const float*)d_in[4];
  const float* mlp_w = (const float*)d_in[5];
  const float* mlp_b = (const float*)d_in[6];
  const float* bn0g  = (const float*)d_in[7];
  const float* bn0b  = (const float*)d_in[8];
  const float* fc1w  = (const float*)d_in[9];
  const float* fc1b  = (const float*)d_in[10];
  const float* bn1g  = (const float*)d_in[11];
  const float* bn1b  = (const float*)d_in[12];
  const float* fc2w  = (const float*)d_in[13];
  const float* fc2b  = (const float*)d_in[14];
  const float* bn2g  = (const float*)d_in[15];
  const float* bn2b  = (const float*)d_in[16];
  const float* fc3w  = (const float*)d_in[17];
  const float* fc3b  = (const float*)d_in[18];
  const float* bn3g  = (const float*)d_in[19];
  const float* bn3b  = (const float*)d_in[20];
  const int* eidx    = (const int*)d_in[21];
  const int* batch   = (const int*)d_in[22];
  float* out = (float*)d_out;

  char* base = (char*)d_ws;
  size_t off = 0;
  auto take = [&](size_t bytes) -> char* {
    char* p = base + off;
    off += (bytes + 255) & ~(size_t)255;
    return p;
  };
  unsigned short* xp   = (unsigned short*)take((size_t)N_NODES * 256 * 2);
  unsigned short* ybf  = (unsigned short*)take((size_t)30016 * 256 * 2);
  unsigned short* wth  = (unsigned short*)take(448 * 256 * 2);
  unsigned short* mwth = (unsigned short*)take(128 * 256 * 2);
  unsigned short* mwtl = (unsigned short*)take(128 * 256 * 2);
  float* a_s = (float*)take((size_t)N_NODES * 2 * 4);
  float* a_d = (float*)take((size_t)N_NODES * 2 * 4);
  int* deg   = (int*)take((size_t)N_NODES * 4);
  int* offs  = (int*)take((size_t)(N_NODES + 1) * 4);
  int* cur   = (int*)take((size_t)N_NODES * 4);
  int* csr   = (int*)take((size_t)N_EDGES * 4);
  float* S   = (float*)take(NGRAPH * 128 * 4);
  float* Q   = (float*)take(128 * 4);
  int* cnt   = (int*)take(NGRAPH * 4);
  float* z1t = (float*)take(512 * 64 * 4);
  float* z2t = (float*)take(256 * 64 * 4);

  hipMemsetAsync(deg, 0, (size_t)N_NODES * 4, stream);
  hipMemsetAsync(S, 0, (size_t)(NGRAPH * 128 * 4 + 512), stream);

  prep_kernel<<<975, 256, 0, stream>>>(eidx, deg, gat_w, mlp_w, wth, mwth, mwtl, batch, cnt);
  scan_kernel<<<1, 1024, 0, stream>>>(deg, offs, cur, N_NODES);
  scatter_kernel<<<938, 256, 0, stream>>>(eidx, cur, csr);
  gat_gemm_kernel<<<938, 256, 0, stream>>>(x, wth, a_src, a_dst, xp, a_s, a_d);
  attn_kernel<<<7500, 256, 0, stream>>>(xp, a_s, a_d, offs, csr, gbias, ybf);
  mlp_gemm_kernel<<<469, 256, 0, stream>>>(ybf, mwth, mwtl, mlp_b, batch, S, Q);
  fc1_kernel<<<128, 256, 0, stream>>>(S, Q, cnt, bn0g, bn0b, fc1w, fc1b, bn1g, bn1b, z1t);
  fc2_kernel<<<64, 256, 0, stream>>>(z1t, fc2w, fc2b, bn2g, bn2b, z2t);
  fc3_kernel<<<1, 64, 0, stream>>>(z2t, fc3w, fc3b, bn3g, bn3b, out);

  (void)in_sizes; (void)n_in; (void)out_size; (void)ws_size;
}

// Round 10
// 361.397 us; speedup vs baseline: 1.2619x; 1.2619x over previous
//
#include <hip/hip_runtime.h>

#define N_NODES 30000
#define N_EDGES 960000
#define NGRAPH  64
#define BN_EPS  1e-5f
#define NBUCKET 118        // ceil(30000/256) — bucket = 256 consecutive dst nodes
#define BCAP    10240      // per-bucket capacity; mean 8192, sd ~90 -> 22 sigma slack
#define GC_STRIDE 16       // gcur padded to one counter per 64B line (atomic chains parallelize per line)

typedef __bf16 bf16x8 __attribute__((ext_vector_type(8)));
typedef float  f32x4  __attribute__((ext_vector_type(4)));

__device__ __forceinline__ unsigned short f2bf(float f) {
  union { float f; unsigned u; } v; v.f = f;
  unsigned r = (v.u + 0x7FFFu + ((v.u >> 16) & 1u)) >> 16;
  return (unsigned short)r;
}
__device__ __forceinline__ float bf2f(unsigned short u) {
  union { unsigned u; float f; } v; v.u = ((unsigned)u) << 16;
  return v.f;
}
__device__ __forceinline__ float bflo(unsigned w) {
  union { unsigned u; float f; } v; v.u = w << 16; return v.f;
}
__device__ __forceinline__ float bfhi(unsigned w) {
  union { unsigned u; float f; } v; v.u = w & 0xFFFF0000u; return v.f;
}
__device__ __forceinline__ void gld_lds16(const void* g, void* l) {
  __builtin_amdgcn_global_load_lds(
      (const __attribute__((address_space(1))) unsigned int*)g,
      (__attribute__((address_space(3))) unsigned int*)l, 16, 0, 0);
}

// ---------------- prep: edge binning (938) + weight transpose-cast (36) + cnt (1) ----------------
__global__ void prep_kernel(const int* __restrict__ ei,
                            int2* __restrict__ binbuf, int* __restrict__ gcur,
                            const float* __restrict__ gw, const float* __restrict__ mw,
                            unsigned short* __restrict__ wth,
                            unsigned short* __restrict__ mwth, unsigned short* __restrict__ mwtl,
                            const int* __restrict__ batch, int* __restrict__ cnt) {
  int b = blockIdx.x;
  int tid = threadIdx.x;
  if (b < 938) {
    // ---- Pass A: bin edges by dst>>8 ----
    __shared__ int lcnt[NBUCKET], lbase[NBUCKET], lcur[NBUCKET];
    int i = b * 1024 + tid * 4;
    bool val = i < N_EDGES;
    int4 dv = {0, 0, 0, 0}, sv = {0, 0, 0, 0};
    if (val) {
      dv = *(const int4*)(ei + N_EDGES + i);
      sv = *(const int4*)(ei + i);
    }
    if (tid < NBUCKET) lcnt[tid] = 0;
    __syncthreads();
    int bk0 = dv.x >> 8, bk1 = dv.y >> 8, bk2 = dv.z >> 8, bk3 = dv.w >> 8;
    if (val) {
      atomicAdd(&lcnt[bk0], 1); atomicAdd(&lcnt[bk1], 1);
      atomicAdd(&lcnt[bk2], 1); atomicAdd(&lcnt[bk3], 1);
    }
    __syncthreads();
    if (tid < NBUCKET) {
      int c = lcnt[tid];
      lbase[tid] = c ? atomicAdd(&gcur[tid * GC_STRIDE], c) : 0;
      lcur[tid] = 0;
    }
    __syncthreads();
    if (val) {
      int s0 = atomicAdd(&lcur[bk0], 1);
      binbuf[(size_t)bk0 * BCAP + lbase[bk0] + s0] = make_int2(sv.x, dv.x);
      int s1 = atomicAdd(&lcur[bk1], 1);
      binbuf[(size_t)bk1 * BCAP + lbase[bk1] + s1] = make_int2(sv.y, dv.y);
      int s2 = atomicAdd(&lcur[bk2], 1);
      binbuf[(size_t)bk2 * BCAP + lbase[bk2] + s2] = make_int2(sv.z, dv.z);
      int s3 = atomicAdd(&lcur[bk3], 1);
      binbuf[(size_t)bk3 * BCAP + lbase[bk3] + s3] = make_int2(sv.w, dv.w);
    }
    return;
  }
  if (b == 974) {
    if (tid < 64) {
      int g = tid;
      int lo = 0, hi = N_NODES;
      while (lo < hi) { int mid = (lo + hi) >> 1; if (batch[mid] < g) lo = mid + 1; else hi = mid; }
      int start = lo;
      lo = 0; hi = N_NODES;
      while (lo < hi) { int mid = (lo + hi) >> 1; if (batch[mid] < g + 1) lo = mid + 1; else hi = mid; }
      cnt[g] = lo - start;
    }
    return;
  }
  // ---- weight transpose-cast ----
  __shared__ float T[64][65];
  int b2 = b - 938;   // 0..35
  const float* src; unsigned short *dh, *dl; int K, Nn, kt, nt;
  if (b2 < 28) { src = gw; dh = wth; dl = nullptr; K = 448; Nn = 256; kt = b2 >> 2; nt = b2 & 3; }
  else { int b3 = b2 - 28; src = mw; dh = mwth; dl = mwtl; K = 256; Nn = 128; kt = b3 >> 1; nt = b3 & 1; }
  int nl = tid & 63, kg = tid >> 6;
#pragma unroll
  for (int j = 0; j < 16; ++j) {
    int k = kt * 64 + kg * 16 + j;
    T[kg * 16 + j][nl] = src[(size_t)k * Nn + nt * 64 + nl];
  }
  __syncthreads();
#pragma unroll
  for (int j = 0; j < 16; ++j) {
    int n = nt * 64 + kg * 16 + j;
    float v = T[nl][kg * 16 + j];
    unsigned short h = f2bf(v);
    size_t o = (size_t)n * K + kt * 64 + nl;
    dh[o] = h;
    if (dl) dl[o] = f2bf(v - bf2f(h));
  }
}

// ---------------- Pass B: per-bucket local CSR build, fully LDS-staged ----------------
// 118 blocks x 256 threads. Reads its bucket contiguously, builds offs + csr segment,
// writes both coalesced. Replaces hist+scan+scatter (scatter alone was 66us: 65MB of
// random-line write-back for a 3.8MB array).
__global__ void __launch_bounds__(256) build_kernel(
    const int2* __restrict__ binbuf, const int* __restrict__ gcur,
    int* __restrict__ offs, int* __restrict__ csr) {
  __shared__ int csrL[BCAP];          // 40KB
  __shared__ int lcnt[256], lofs[256];
  __shared__ int wsum[4], wpre[4];
  __shared__ int redsum;
  int b = blockIdx.x, tid = threadIdx.x;
  int wv = tid >> 6, lane = tid & 63;
  int n0 = b * 256;
  int ecnt = gcur[b * GC_STRIDE];
  // cbase = sum of bucket counts before b
  if (tid == 0) redsum = 0;
  lcnt[tid] = 0;
  __syncthreads();
  {
    int v = (tid < b) ? gcur[tid * GC_STRIDE] : 0;
#pragma unroll
    for (int o = 32; o; o >>= 1) v += __shfl_xor(v, o);
    if (lane == 0) atomicAdd(&redsum, v);
  }
  __syncthreads();
  int cbase = redsum;
  const int2* bp = binbuf + (size_t)b * BCAP;
  // local histogram
  for (int e = tid; e < ecnt; e += 256) atomicAdd(&lcnt[bp[e].y - n0], 1);
  __syncthreads();
  // exclusive scan of 256 counts
  int c = lcnt[tid];
  int s = c;
#pragma unroll
  for (int o = 1; o <= 32; o <<= 1) {
    int t = __shfl_up(s, o, 64);
    if (lane >= o) s += t;
  }
  if (lane == 63) wsum[wv] = s;
  __syncthreads();
  if (tid == 0) {
    int a = 0;
#pragma unroll
    for (int j = 0; j < 4; ++j) { wpre[j] = a; a += wsum[j]; }
  }
  __syncthreads();
  int excl = wpre[wv] + s - c;
  lofs[tid] = excl;
  int node = n0 + tid;
  if (node < N_NODES) offs[node] = cbase + excl;
  if (b == NBUCKET - 1 && tid == 0) offs[N_NODES] = cbase + ecnt;  // == N_EDGES
  lcnt[tid] = 0;                      // reuse as cursor
  __syncthreads();
  // local scatter into LDS
  for (int e = tid; e < ecnt; e += 256) {
    int2 p = bp[e];
    int li = p.y - n0;
    int pos = lofs[li] + atomicAdd(&lcnt[li], 1);
    csrL[pos] = p.x;
  }
  __syncthreads();
  // coalesced write-out
  for (int e = tid; e < ecnt; e += 256) csr[cbase + e] = csrL[e];
}

// ---------------- GEMM1: A direct-to-registers, only B through LDS ----------------
__global__ void __launch_bounds__(256) gat_gemm_kernel(
    const float* __restrict__ x,
    const unsigned short* __restrict__ wth,
    const float* __restrict__ asrc, const float* __restrict__ adst,
    unsigned short* __restrict__ xp, float* __restrict__ a_s, float* __restrict__ a_d) {
  __shared__ unsigned short Bh[4 * 128 * 8];   // 8KB, [q][n][8]
  int tid = threadIdx.x;
  int w = tid >> 6, lane = tid & 63;
  int m = lane & 15, quad = lane >> 4;
  int rt = blockIdx.x >> 1, ch = blockIdx.x & 1;
  int r0 = rt * 64;
  int arow = r0 + w * 16 + m;
  int arc = min(arow, N_NODES - 1);
  const float* ap = x + (size_t)arc * 448 + quad * 8;
  const unsigned short* bsh = wth + (size_t)(ch * 128) * 448;

  f32x4 acc[8];
#pragma unroll
  for (int c = 0; c < 8; ++c) acc[c] = (f32x4){0.f, 0.f, 0.f, 0.f};

  for (int kc = 0; kc < 14; ++kc) {
    int k0 = kc * 32;
#pragma unroll
    for (int i = 0; i < 2; ++i)
      gld_lds16(bsh + (size_t)(i * 64 + lane) * 448 + k0 + w * 8, Bh + w * 1024 + i * 512);
    float av[8];
    *(float4*)(av) = *(const float4*)(ap + k0);
    *(float4*)(av + 4) = *(const float4*)(ap + k0 + 4);
    bf16x8 ah, al;
#pragma unroll
    for (int j = 0; j < 8; ++j) {
      unsigned short h = f2bf(av[j]);
      unsigned short l = f2bf(av[j] - bf2f(h));
      ah[j] = *(__bf16*)&h;
      al[j] = *(__bf16*)&l;
    }
    __syncthreads();
#pragma unroll
    for (int c = 0; c < 8; ++c) {
      bf16x8 bh = *(const bf16x8*)(Bh + quad * 1024 + (c * 16 + m) * 8);
      acc[c] = __builtin_amdgcn_mfma_f32_16x16x32_bf16(ah, bh, acc[c], 0, 0, 0);
      acc[c] = __builtin_amdgcn_mfma_f32_16x16x32_bf16(al, bh, acc[c], 0, 0, 0);
    }
    __syncthreads();
  }
  float ps[4] = {0, 0, 0, 0}, pd[4] = {0, 0, 0, 0};
#pragma unroll
  for (int c = 0; c < 8; ++c) {
    int col = ch * 128 + c * 16 + m;
    float sa = asrc[col], da = adst[col];
#pragma unroll
    for (int r = 0; r < 4; ++r) {
      float v = acc[c][r];
      ps[r] += v * sa; pd[r] += v * da;
    }
  }
#pragma unroll
  for (int o = 1; o <= 8; o <<= 1) {
#pragma unroll
    for (int r = 0; r < 4; ++r) {
      ps[r] += __shfl_xor(ps[r], o);
      pd[r] += __shfl_xor(pd[r], o);
    }
  }
  int rowb = r0 + w * 16 + quad * 4;
  if (m == 0) {
#pragma unroll
    for (int r = 0; r < 4; ++r) {
      int row = rowb + r;
      if (row < N_NODES) {
        a_s[2 * row + ch] = ps[r];
        a_d[2 * row + ch] = pd[r];
      }
    }
  }
#pragma unroll
  for (int r = 0; r < 4; ++r) {
    int row = rowb + r;
    if (row < N_NODES) {
#pragma unroll
      for (int c = 0; c < 8; ++c)
        xp[(size_t)row * 256 + ch * 128 + c * 16 + m] = f2bf(acc[c][r]);
    }
  }
}

// ---------------- attention: one wave per dst node; 16 edges/iter ----------------
__global__ void attn_kernel(const unsigned short* __restrict__ xp,
                            const float* __restrict__ a_s, const float* __restrict__ a_d,
                            const int* __restrict__ offs, const int* __restrict__ csr,
                            const float* __restrict__ bias, unsigned short* __restrict__ y) {
  int nid = (blockIdx.x * 256 + (int)threadIdx.x) >> 6;
  int lane = threadIdx.x & 63;
  int l32 = lane & 31;
  int grp = lane >> 5;
  int h2 = l32 >> 4;
  float d0 = a_d[2 * nid], d1 = a_d[2 * nid + 1];
  float s0 = a_s[2 * nid], s1 = a_s[2 * nid + 1];
  int beg = offs[nid], end = offs[nid + 1];
  int deg = end - beg;
  float e0s = s0 + d0; e0s = e0s > 0.f ? e0s : 0.2f * e0s;
  float e1s = s1 + d1; e1s = e1s > 0.f ? e1s : 0.2f * e1s;

  if (deg <= 64) {
    int sreg = nid;
    float p0 = 0.f, p1 = 0.f;
    float e0 = -1e30f, e1 = -1e30f;
    if (lane < deg) {
      sreg = csr[beg + lane];
      float as0 = a_s[2 * sreg], as1 = a_s[2 * sreg + 1];
      e0 = as0 + d0; e0 = e0 > 0.f ? e0 : 0.2f * e0;
      e1 = as1 + d1; e1 = e1 > 0.f ? e1 : 0.2f * e1;
    }
    float m0 = fmaxf(e0, e0s), m1 = fmaxf(e1, e1s);
#pragma unroll
    for (int o = 32; o; o >>= 1) {
      m0 = fmaxf(m0, __shfl_xor(m0, o));
      m1 = fmaxf(m1, __shfl_xor(m1, o));
    }
    if (lane < deg) { p0 = __expf(e0 - m0); p1 = __expf(e1 - m1); }
    float ws0 = p0, ws1 = p1;
#pragma unroll
    for (int o = 32; o; o >>= 1) { ws0 += __shfl_xor(ws0, o); ws1 += __shfl_xor(ws1, o); }
    float wself0 = __expf(e0s - m0), wself1 = __expf(e1s - m1);
    float inv = 1.f / (h2 ? (ws1 + wself1) : (ws0 + wself0));

    float acc[8] = {0.f, 0.f, 0.f, 0.f, 0.f, 0.f, 0.f, 0.f};
    const unsigned* xpw = (const unsigned*)xp;
    {
      float wgt = grp ? 0.f : (h2 ? wself1 : wself0);
      uint4 u = *(const uint4*)(xpw + (size_t)nid * 128 + l32 * 4);
      acc[0] += wgt * bflo(u.x); acc[1] += wgt * bfhi(u.x);
      acc[2] += wgt * bflo(u.y); acc[3] += wgt * bfhi(u.y);
      acc[4] += wgt * bflo(u.z); acc[5] += wgt * bfhi(u.z);
      acc[6] += wgt * bflo(u.w); acc[7] += wgt * bfhi(u.w);
    }
    for (int j0 = 0; j0 < deg; j0 += 16) {
      int si[8]; float g[8];
#pragma unroll
      for (int i = 0; i < 8; ++i) {
        int e = j0 + 2 * i + grp;
        si[i] = __shfl(sreg, e);
        float a0 = __shfl(p0, e), a1 = __shfl(p1, e);
        g[i] = h2 ? a1 : a0;
      }
      uint4 u[8];
#pragma unroll
      for (int i = 0; i < 8; ++i)
        u[i] = *(const uint4*)(xpw + (size_t)si[i] * 128 + l32 * 4);
#pragma unroll
      for (int i = 0; i < 8; ++i) {
        acc[0] += g[i] * bflo(u[i].x); acc[1] += g[i] * bfhi(u[i].x);
        acc[2] += g[i] * bflo(u[i].y); acc[3] += g[i] * bfhi(u[i].y);
        acc[4] += g[i] * bflo(u[i].z); acc[5] += g[i] * bfhi(u[i].z);
        acc[6] += g[i] * bflo(u[i].w); acc[7] += g[i] * bfhi(u[i].w);
      }
    }
#pragma unroll
    for (int i = 0; i < 8; ++i) acc[i] += __shfl_xor(acc[i], 32);
    if (grp == 0) {
      int c0 = l32 * 8;
      float4 b0 = *(const float4*)(bias + c0);
      float4 b1 = *(const float4*)(bias + c0 + 4);
      float ob[8] = {b0.x, b0.y, b0.z, b0.w, b1.x, b1.y, b1.z, b1.w};
      unsigned short h[8];
#pragma unroll
      for (int i = 0; i < 8; ++i) {
        float v = acc[i] * inv + ob[i];
        v = v > 0.f ? v : __expf(v) - 1.f;
        h[i] = f2bf(v);
      }
      uint4 o;
      o.x = (unsigned)h[0] | ((unsigned)h[1] << 16);
      o.y = (unsigned)h[2] | ((unsigned)h[3] << 16);
      o.z = (unsigned)h[4] | ((unsigned)h[5] << 16);
      o.w = (unsigned)h[6] | ((unsigned)h[7] << 16);
      *(uint4*)(y + (size_t)nid * 256 + c0) = o;
    }
    return;
  }

  // slow path (deg > 64)
  int head = lane >> 5;
  float m0 = e0s, m1 = e1s;
  for (int j = beg + lane; j < end; j += 64) {
    int s = csr[j];
    float as0 = a_s[2 * s], as1 = a_s[2 * s + 1];
    float e0 = as0 + d0; e0 = e0 > 0.f ? e0 : 0.2f * e0;
    float e1 = as1 + d1; e1 = e1 > 0.f ? e1 : 0.2f * e1;
    m0 = fmaxf(m0, e0); m1 = fmaxf(m1, e1);
  }
#pragma unroll
  for (int o = 32; o; o >>= 1) {
    m0 = fmaxf(m0, __shfl_xor(m0, o));
    m1 = fmaxf(m1, __shfl_xor(m1, o));
  }
  float dh = head ? d1 : d0;
  float mh = head ? m1 : m0;
  float ax, ay, az, aw, wsum;
  {
    float e = head ? e1s : e0s;
    float wgt = __expf(e - mh);
    ushort4 u = *(const ushort4*)(xp + (size_t)nid * 256 + lane * 4);
    ax = wgt * bf2f(u.x); ay = wgt * bf2f(u.y); az = wgt * bf2f(u.z); aw = wgt * bf2f(u.w);
    wsum = wgt;
  }
  for (int j = beg; j < end; ++j) {
    int s = csr[j];
    float as = a_s[2 * s + head];
    float e = as + dh; e = e > 0.f ? e : 0.2f * e;
    float wgt = __expf(e - mh);
    ushort4 u = *(const ushort4*)(xp + (size_t)s * 256 + lane * 4);
    ax += wgt * bf2f(u.x); ay += wgt * bf2f(u.y); az += wgt * bf2f(u.z); aw += wgt * bf2f(u.w);
    wsum += wgt;
  }
  float inv = 1.f / wsum;
  float4 b4 = *(const float4*)(bias + lane * 4);
  float o0 = ax * inv + b4.x, o1 = ay * inv + b4.y;
  float o2 = az * inv + b4.z, o3 = aw * inv + b4.w;
  o0 = o0 > 0.f ? o0 : __expf(o0) - 1.f;
  o1 = o1 > 0.f ? o1 : __expf(o1) - 1.f;
  o2 = o2 > 0.f ? o2 : __expf(o2) - 1.f;
  o3 = o3 > 0.f ? o3 : __expf(o3) - 1.f;
  ushort4 yo; yo.x = f2bf(o0); yo.y = f2bf(o1); yo.z = f2bf(o2); yo.w = f2bf(o3);
  *(ushort4*)(y + (size_t)nid * 256 + lane * 4) = yo;
}

// ---------------- GEMM2: A direct-from-global, B split via LDS ----------------
__global__ void __launch_bounds__(256) mlp_gemm_kernel(
    const unsigned short* __restrict__ y,
    const unsigned short* __restrict__ mwth, const unsigned short* __restrict__ mwtl,
    const float* __restrict__ mlp_b, const int* __restrict__ batch,
    float* __restrict__ S, float* __restrict__ Q) {
  __shared__ unsigned short Bh[4 * 128 * 8], Bl[4 * 128 * 8];
  __shared__ float Sloc[128], Qloc[128];
  int tid = threadIdx.x;
  int w = tid >> 6, lane = tid & 63;
  int m = lane & 15, quad = lane >> 4;
  int r0 = blockIdx.x * 64;
  if (tid < 128) { Sloc[tid] = 0.f; Qloc[tid] = 0.f; }
  const unsigned short* ap = y + (size_t)(r0 + w * 16 + m) * 256 + quad * 8;

  f32x4 acc[8];
#pragma unroll
  for (int c = 0; c < 8; ++c) acc[c] = (f32x4){0.f, 0.f, 0.f, 0.f};

  for (int kc = 0; kc < 8; ++kc) {
    int k0 = kc * 32;
#pragma unroll
    for (int i = 0; i < 2; ++i) {
      int n = i * 64 + lane;
      gld_lds16(mwth + (size_t)n * 256 + k0 + w * 8, Bh + w * 1024 + i * 512);
      gld_lds16(mwtl + (size_t)n * 256 + k0 + w * 8, Bl + w * 1024 + i * 512);
    }
    bf16x8 ah = *(const bf16x8*)(ap + k0);
    __syncthreads();
#pragma unroll
    for (int c = 0; c < 8; ++c) {
      bf16x8 bh = *(const bf16x8*)(Bh + quad * 1024 + (c * 16 + m) * 8);
      bf16x8 bl = *(const bf16x8*)(Bl + quad * 1024 + (c * 16 + m) * 8);
      acc[c] = __builtin_amdgcn_mfma_f32_16x16x32_bf16(ah, bh, acc[c], 0, 0, 0);
      acc[c] = __builtin_amdgcn_mfma_f32_16x16x32_bf16(ah, bl, acc[c], 0, 0, 0);
    }
    __syncthreads();
  }
  int rowb = r0 + w * 16 + quad * 4;
  int gfirst = batch[r0];
  int glast = batch[min(r0 + 63, N_NODES - 1)];
  bool uni = (gfirst == glast);
  bool valid[4]; int gg[4];
#pragma unroll
  for (int r = 0; r < 4; ++r) {
    int row = rowb + r;
    valid[r] = row < N_NODES;
    gg[r] = (!uni && valid[r]) ? batch[row] : gfirst;
  }
#pragma unroll
  for (int c = 0; c < 8; ++c) {
    int col = c * 16 + m;
    float bv = mlp_b[col];
    float sc = 0.f, qc = 0.f;
#pragma unroll
    for (int r = 0; r < 4; ++r) {
      if (valid[r]) {
        float v = acc[c][r] + bv;
        qc += v * v;
        if (uni) sc += v;
        else atomicAdd(&S[gg[r] * 128 + col], v);
      }
    }
    qc += __shfl_xor(qc, 16); qc += __shfl_xor(qc, 32);
    sc += __shfl_xor(sc, 16); sc += __shfl_xor(sc, 32);
    if (quad == 0) {
      atomicAdd(&Qloc[col], qc);
      if (uni) atomicAdd(&Sloc[col], sc);
    }
  }
  __syncthreads();
  if (tid < 128) {
    atomicAdd(&Q[tid], Qloc[tid]);
    if (uni) atomicAdd(&S[gfirst * 128 + tid], Sloc[tid]);
  }
}

// ---------------- FC head ----------------
__global__ void fc1_kernel(const float* __restrict__ S, const float* __restrict__ Q,
                           const int* __restrict__ cnt, const float* __restrict__ g0,
                           const float* __restrict__ b0,
                           const float* __restrict__ w, const float* __restrict__ b,
                           const float* __restrict__ bng, const float* __restrict__ bnb,
                           float* __restrict__ z1t) {
  __shared__ float hp[64 * 129];
  int tid = threadIdx.x;
  if (tid < 128) {
    int c = tid;
    float sum = 0.f;
    for (int g = 0; g < NGRAPH; ++g) sum += S[g * 128 + c];
    float mu = sum / (float)N_NODES;
    float var = Q[c] / (float)N_NODES - mu * mu;
    float gam = g0[c] * rsqrtf(var + BN_EPS);
    float bet = b0[c];
    for (int g = 0; g < NGRAPH; ++g) {
      float k = (float)cnt[g];
      hp[g * 129 + c] = gam * (S[g * 128 + c] - k * mu) + k * bet;
    }
  }
  __syncthreads();
  int wv = tid >> 6, lane = tid & 63;
  int j = blockIdx.x * 4 + wv;
  float acc = b[j];
  for (int c = 0; c < 128; ++c) acc += hp[lane * 129 + c] * w[c * 512 + j];
  float s1 = acc, s2 = acc * acc;
#pragma unroll
  for (int o = 32; o; o >>= 1) { s1 += __shfl_xor(s1, o); s2 += __shfl_xor(s2, o); }
  float mu = s1 * (1.f / 64.f), var = s2 * (1.f / 64.f) - mu * mu;
  float z = bng[j] * (acc - mu) * rsqrtf(var + BN_EPS) + bnb[j];
  z1t[j * 64 + lane] = fmaxf(z, 0.f);
}

__global__ void fc2_kernel(const float* __restrict__ z1t, const float* __restrict__ w,
                           const float* __restrict__ b, const float* __restrict__ bng,
                           const float* __restrict__ bnb, float* __restrict__ z2t) {
  int wv = threadIdx.x >> 6, lane = threadIdx.x & 63;
  int j = blockIdx.x * 4 + wv;
  float acc = b[j];
  for (int c = 0; c < 512; ++c) acc += z1t[c * 64 + lane] * w[c * 256 + j];
  float s1 = acc, s2 = acc * acc;
#pragma unroll
  for (int o = 32; o; o >>= 1) { s1 += __shfl_xor(s1, o); s2 += __shfl_xor(s2, o); }
  float mu = s1 * (1.f / 64.f), var = s2 * (1.f / 64.f) - mu * mu;
  float z = bng[j] * (acc - mu) * rsqrtf(var + BN_EPS) + bnb[j];
  z2t[j * 64 + lane] = fmaxf(z, 0.f);
}

__global__ void fc3_kernel(const float* __restrict__ z2t, const float* __restrict__ w,
                           const float* __restrict__ b, const float* __restrict__ bng,
                           const float* __restrict__ bnb, float* __restrict__ out) {
  int lane = threadIdx.x;
  float acc = b[0];
  for (int c = 0; c < 256; ++c) acc += z2t[c * 64 + lane] * w[c];
  float s1 = acc, s2 = acc * acc;
#pragma unroll
  for (int o = 32; o; o >>= 1) { s1 += __shfl_xor(s1, o); s2 += __shfl_xor(s2, o); }
  float mu = s1 * (1.f / 64.f), var = s2 * (1.f / 64.f) - mu * mu;
  out[lane] = bng[0] * (acc - mu) * rsqrtf(var + BN_EPS) + bnb[0];
}

extern "C" void kernel_launch(void* const* d_in, const int* in_sizes, int n_in,
                              void* d_out, int out_size, void* d_ws, size_t ws_size,
                              hipStream_t stream) {
  const float* x     = (const float*)d_in[0];
  const float* gat_w = (const float*)d_in[1];
  const float* a_src = (const float*)d_in[2];
  const float* a_dst = (const float*)d_in[3];
  const float* gbias = (const float*)d_in[4];
  const float* mlp_w = (const float*)d_in[5];
  const float* mlp_b = (const float*)d_in[6];
  const float* bn0g  = (const float*)d_in[7];
  const float* bn0b  = (const float*)d_in[8];
  const float* fc1w  = (const float*)d_in[9];
  const float* fc1b  = (const float*)d_in[10];
  const float* bn1g  = (const float*)d_in[11];
  const float* bn1b  = (const float*)d_in[12];
  const float* fc2w  = (const float*)d_in[13];
  const float* fc2b  = (const float*)d_in[14];
  const float* bn2g  = (const float*)d_in[15];
  const float* bn2b  = (const float*)d_in[16];
  const float* fc3w  = (const float*)d_in[17];
  const float* fc3b  = (const float*)d_in[18];
  const float* bn3g  = (const float*)d_in[19];
  const float* bn3b  = (const float*)d_in[20];
  const int* eidx    = (const int*)d_in[21];
  const int* batch   = (const int*)d_in[22];
  float* out = (float*)d_out;

  char* base = (char*)d_ws;
  size_t off = 0;
  auto take = [&](size_t bytes) -> char* {
    char* p = base + off;
    off += (bytes + 255) & ~(size_t)255;
    return p;
  };
  unsigned short* xp   = (unsigned short*)take((size_t)N_NODES * 256 * 2);
  unsigned short* ybf  = (unsigned short*)take((size_t)30016 * 256 * 2);
  unsigned short* wth  = (unsigned short*)take(448 * 256 * 2);
  unsigned short* mwth = (unsigned short*)take(128 * 256 * 2);
  unsigned short* mwtl = (unsigned short*)take(128 * 256 * 2);
  float* a_s = (float*)take((size_t)N_NODES * 2 * 4);
  float* a_d = (float*)take((size_t)N_NODES * 2 * 4);
  int* offs  = (int*)take((size_t)(N_NODES + 1) * 4);
  int* csr   = (int*)take((size_t)N_EDGES * 4);
  int2* binbuf = (int2*)take((size_t)NBUCKET * BCAP * 8);
  int* gcur  = (int*)take((size_t)NBUCKET * GC_STRIDE * 4);
  float* S   = (float*)take(NGRAPH * 128 * 4);
  float* Q   = (float*)take(128 * 4);
  int* cnt   = (int*)take(NGRAPH * 4);
  float* z1t = (float*)take(512 * 64 * 4);
  float* z2t = (float*)take(256 * 64 * 4);

  hipMemsetAsync(gcur, 0, (size_t)NBUCKET * GC_STRIDE * 4, stream);
  hipMemsetAsync(S, 0, (size_t)(NGRAPH * 128 * 4 + 512), stream);

  prep_kernel<<<975, 256, 0, stream>>>(eidx, binbuf, gcur, gat_w, mlp_w,
                                       wth, mwth, mwtl, batch, cnt);
  build_kernel<<<NBUCKET, 256, 0, stream>>>(binbuf, gcur, offs, csr);
  gat_gemm_kernel<<<938, 256, 0, stream>>>(x, wth, a_src, a_dst, xp, a_s, a_d);
  attn_kernel<<<7500, 256, 0, stream>>>(xp, a_s, a_d, offs, csr, gbias, ybf);
  mlp_gemm_kernel<<<469, 256, 0, stream>>>(ybf, mwth, mwtl, mlp_b, batch, S, Q);
  fc1_kernel<<<128, 256, 0, stream>>>(S, Q, cnt, bn0g, bn0b, fc1w, fc1b, bn1g, bn1b, z1t);
  fc2_kernel<<<64, 256, 0, stream>>>(z1t, fc2w, fc2b, bn2g, bn2b, z2t);
  fc3_kernel<<<1, 64, 0, stream>>>(z2t, fc3w, fc3b, bn3g, bn3b, out);

  (void)in_sizes; (void)n_in; (void)out_size; (void)ws_size;
}

// Round 11
// 334.300 us; speedup vs baseline: 1.3641x; 1.0811x over previous
//
#include <hip/hip_runtime.h>

#define N_NODES 30000
#define N_EDGES 960000
#define NGRAPH  64
#define BN_EPS  1e-5f
#define NBUCKET 118        // bucket = 256 consecutive dst nodes
#define BCAP    8960       // mean 8192, sd ~90 -> +8.5 sigma
#define GC_STRIDE 16
#define BLD_N   118

typedef __bf16 bf16x8 __attribute__((ext_vector_type(8)));
typedef float  f32x4  __attribute__((ext_vector_type(4)));

__device__ __forceinline__ unsigned short f2bf(float f) {
  union { float f; unsigned u; } v; v.f = f;
  unsigned r = (v.u + 0x7FFFu + ((v.u >> 16) & 1u)) >> 16;
  return (unsigned short)r;
}
__device__ __forceinline__ float bf2f(unsigned short u) {
  union { unsigned u; float f; } v; v.u = ((unsigned)u) << 16;
  return v.f;
}
__device__ __forceinline__ float bflo(unsigned w) {
  union { unsigned u; float f; } v; v.u = w << 16; return v.f;
}
__device__ __forceinline__ float bfhi(unsigned w) {
  union { unsigned u; float f; } v; v.u = w & 0xFFFF0000u; return v.f;
}
__device__ __forceinline__ void gld_lds16(const void* g, void* l) {
  __builtin_amdgcn_global_load_lds(
      (const __attribute__((address_space(1))) unsigned int*)g,
      (__attribute__((address_space(3))) unsigned int*)l, 16, 0, 0);
}

// ---------------- prep: edge binning w/ LDS sort (938) + weight cast (36) + cnt (1) ----------------
__global__ void prep_kernel(const int* __restrict__ ei,
                            int2* __restrict__ binbuf, int* __restrict__ gcur,
                            const float* __restrict__ gw, const float* __restrict__ mw,
                            unsigned short* __restrict__ wth,
                            unsigned short* __restrict__ mwth, unsigned short* __restrict__ mwtl,
                            const int* __restrict__ batch, int* __restrict__ cnt) {
  int b = blockIdx.x;
  int tid = threadIdx.x;
  if (b < 938) {
    __shared__ int lcnt[NBUCKET], lofs[NBUCKET], lbase[NBUCKET];
    __shared__ int2 ebuf[1024];
    int i = b * 1024 + tid * 4;
    bool val = i < N_EDGES;
    int4 dv = {0, 0, 0, 0}, sv = {0, 0, 0, 0};
    if (val) {
      dv = *(const int4*)(ei + N_EDGES + i);
      sv = *(const int4*)(ei + i);
    }
    if (tid < NBUCKET) lcnt[tid] = 0;
    __syncthreads();
    int bk0 = dv.x >> 8, bk1 = dv.y >> 8, bk2 = dv.z >> 8, bk3 = dv.w >> 8;
    if (val) {
      atomicAdd(&lcnt[bk0], 1); atomicAdd(&lcnt[bk1], 1);
      atomicAdd(&lcnt[bk2], 1); atomicAdd(&lcnt[bk3], 1);
    }
    __syncthreads();
    if (tid == 0) {
      int run = 0;
      for (int j = 0; j < NBUCKET; ++j) { lofs[j] = run; run += lcnt[j]; }
    }
    __syncthreads();
    if (tid < NBUCKET) {
      int c = lcnt[tid];
      lbase[tid] = c ? atomicAdd(&gcur[tid * GC_STRIDE], c) : 0;
      lcnt[tid] = 0;            // reuse as cursor
    }
    __syncthreads();
    if (val) {
      int s0 = atomicAdd(&lcnt[bk0], 1); ebuf[lofs[bk0] + s0] = make_int2(sv.x, dv.x);
      int s1 = atomicAdd(&lcnt[bk1], 1); ebuf[lofs[bk1] + s1] = make_int2(sv.y, dv.y);
      int s2 = atomicAdd(&lcnt[bk2], 1); ebuf[lofs[bk2] + s2] = make_int2(sv.z, dv.z);
      int s3 = atomicAdd(&lcnt[bk3], 1); ebuf[lofs[bk3] + s3] = make_int2(sv.w, dv.w);
    }
    __syncthreads();
    int tot = min(1024, N_EDGES - b * 1024);
    for (int e = tid; e < tot; e += 256) {
      int2 p = ebuf[e];
      int bk = p.y >> 8;
      binbuf[(size_t)bk * BCAP + lbase[bk] + (e - lofs[bk])] = p;
    }
    return;
  }
  if (b == 974) {
    if (tid < 64) {
      int g = tid;
      int lo = 0, hi = N_NODES;
      while (lo < hi) { int mid = (lo + hi) >> 1; if (batch[mid] < g) lo = mid + 1; else hi = mid; }
      int start = lo;
      lo = 0; hi = N_NODES;
      while (lo < hi) { int mid = (lo + hi) >> 1; if (batch[mid] < g + 1) lo = mid + 1; else hi = mid; }
      cnt[g] = lo - start;
    }
    return;
  }
  // ---- weight transpose-cast ----
  __shared__ float T[64][65];
  int b2 = b - 938;   // 0..35
  const float* src; unsigned short *dh, *dl; int K, Nn, kt, nt;
  if (b2 < 28) { src = gw; dh = wth; dl = nullptr; K = 448; Nn = 256; kt = b2 >> 2; nt = b2 & 3; }
  else { int b3 = b2 - 28; src = mw; dh = mwth; dl = mwtl; K = 256; Nn = 128; kt = b3 >> 1; nt = b3 & 1; }
  int nl = tid & 63, kg = tid >> 6;
#pragma unroll
  for (int j = 0; j < 16; ++j) {
    int k = kt * 64 + kg * 16 + j;
    T[kg * 16 + j][nl] = src[(size_t)k * Nn + nt * 64 + nl];
  }
  __syncthreads();
#pragma unroll
  for (int j = 0; j < 16; ++j) {
    int n = nt * 64 + kg * 16 + j;
    float v = T[nl][kg * 16 + j];
    unsigned short h = f2bf(v);
    size_t o = (size_t)n * K + kt * 64 + nl;
    dh[o] = h;
    if (dl) dl[o] = f2bf(v - bf2f(h));
  }
}

// ---------------- merged: build (blocks 0..117) + GEMM1 (blocks 118..1055) ----------------
// build: per-bucket LDS CSR build (independent of gat; fusing hides its serial time —
// unlike R8's scatter it is LDS-local + coalesced, so it doesn't starve MFMA waves).
// gat: 64 rows x 128 cols (ch == head), A direct-to-regs split-bf16 prefetched one iter
// ahead, B hi-only double-buffered w/ ONE barrier/iter, xp stored via LDS transpose.
__global__ void __launch_bounds__(256) gat_build_kernel(
    const int2* __restrict__ binbuf, const int* __restrict__ gcur,
    int* __restrict__ offs, int* __restrict__ csr,
    const float* __restrict__ x, const unsigned short* __restrict__ wth,
    const float* __restrict__ asrc, const float* __restrict__ adst,
    unsigned short* __restrict__ xp, float* __restrict__ a_s, float* __restrict__ a_d) {
  __shared__ __align__(16) int smemI[9728];    // 38 KB union
  int tid = threadIdx.x;
  int wv = tid >> 6, lane = tid & 63;
  if (blockIdx.x < BLD_N) {
    int* csrL = smemI;                // 8960
    int* lcnt = smemI + 8960;         // 256
    int* lofs = smemI + 9216;         // 256
    int* wsum = smemI + 9472;         // 4
    int* wpre = smemI + 9476;         // 4
    int* redsum = smemI + 9480;
    int b = blockIdx.x;
    int n0 = b * 256;
    int ecnt = gcur[b * GC_STRIDE];
    if (tid == 0) *redsum = 0;
    lcnt[tid] = 0;
    __syncthreads();
    {
      int v = (tid < b) ? gcur[tid * GC_STRIDE] : 0;
#pragma unroll
      for (int o = 32; o; o >>= 1) v += __shfl_xor(v, o);
      if (lane == 0) atomicAdd(redsum, v);
    }
    __syncthreads();
    int cbase = *redsum;
    const int2* bp = binbuf + (size_t)b * BCAP;
    for (int e = tid; e < ecnt; e += 256) atomicAdd(&lcnt[bp[e].y - n0], 1);
    __syncthreads();
    int c = lcnt[tid];
    int s = c;
#pragma unroll
    for (int o = 1; o <= 32; o <<= 1) {
      int t = __shfl_up(s, o, 64);
      if (lane >= o) s += t;
    }
    if (lane == 63) wsum[wv] = s;
    __syncthreads();
    if (tid == 0) {
      int a = 0;
#pragma unroll
      for (int j = 0; j < 4; ++j) { wpre[j] = a; a += wsum[j]; }
    }
    __syncthreads();
    int excl = wpre[wv] + s - c;
    lofs[tid] = excl;
    int node = n0 + tid;
    if (node < N_NODES) offs[node] = cbase + excl;
    if (b == BLD_N - 1 && tid == 0) offs[N_NODES] = cbase + ecnt;
    lcnt[tid] = 0;
    __syncthreads();
    for (int e = tid; e < ecnt; e += 256) {
      int2 p = bp[e];
      int li = p.y - n0;
      int pos = lofs[li] + atomicAdd(&lcnt[li], 1);
      csrL[pos] = p.x;
    }
    __syncthreads();
    for (int e = tid; e < ecnt; e += 256) csr[cbase + e] = csrL[e];
    return;
  }
  // ---------------- gat path ----------------
  int t = (int)blockIdx.x - BLD_N;    // 0..937
  int m = lane & 15, quad = lane >> 4;
  int rt = t >> 1, ch = t & 1;
  int r0 = rt * 64;
  int arow = r0 + wv * 16 + m;
  int arc = min(arow, N_NODES - 1);
  const float* ap = x + (size_t)arc * 448 + quad * 8;
  const unsigned short* bsh = wth + (size_t)(ch * 128) * 448;
  unsigned short* B0 = (unsigned short*)smemI;        // 4096 shorts
  unsigned short* B1 = B0 + 4096;

  f32x4 acc[8];
#pragma unroll
  for (int c = 0; c < 8; ++c) acc[c] = (f32x4){0.f, 0.f, 0.f, 0.f};

  float4 v0 = *(const float4*)(ap);
  float4 v1 = *(const float4*)(ap + 4);
#pragma unroll
  for (int i = 0; i < 2; ++i)
    gld_lds16(bsh + (size_t)(i * 64 + lane) * 448 + wv * 8, B0 + wv * 1024 + i * 512);

  for (int kc = 0; kc < 14; ++kc) {
    unsigned short* Bc = (kc & 1) ? B1 : B0;
    unsigned short* Bn = (kc & 1) ? B0 : B1;
    __syncthreads();                 // B(kc) + A(kc) drained
    float4 p0, p1;
    if (kc < 13) {
      int k0n = (kc + 1) * 32;
#pragma unroll
      for (int i = 0; i < 2; ++i)
        gld_lds16(bsh + (size_t)(i * 64 + lane) * 448 + k0n + wv * 8, Bn + wv * 1024 + i * 512);
      p0 = *(const float4*)(ap + k0n);
      p1 = *(const float4*)(ap + k0n + 4);
    }
    float av[8] = {v0.x, v0.y, v0.z, v0.w, v1.x, v1.y, v1.z, v1.w};
    bf16x8 ah, al;
#pragma unroll
    for (int j = 0; j < 8; ++j) {
      unsigned short h = f2bf(av[j]);
      unsigned short l = f2bf(av[j] - bf2f(h));
      ah[j] = *(__bf16*)&h;
      al[j] = *(__bf16*)&l;
    }
#pragma unroll
    for (int c = 0; c < 8; ++c) {
      bf16x8 bh = *(const bf16x8*)(Bc + quad * 1024 + (c * 16 + m) * 8);
      acc[c] = __builtin_amdgcn_mfma_f32_16x16x32_bf16(ah, bh, acc[c], 0, 0, 0);
      acc[c] = __builtin_amdgcn_mfma_f32_16x16x32_bf16(al, bh, acc[c], 0, 0, 0);
    }
    if (kc < 13) { v0 = p0; v1 = p1; }
  }
  // a_s/a_d epilogue
  float ps[4] = {0, 0, 0, 0}, pd[4] = {0, 0, 0, 0};
#pragma unroll
  for (int c = 0; c < 8; ++c) {
    int col = ch * 128 + c * 16 + m;
    float sa = asrc[col], da = adst[col];
#pragma unroll
    for (int r = 0; r < 4; ++r) {
      float v = acc[c][r];
      ps[r] += v * sa; pd[r] += v * da;
    }
  }
#pragma unroll
  for (int o = 1; o <= 8; o <<= 1) {
#pragma unroll
    for (int r = 0; r < 4; ++r) {
      ps[r] += __shfl_xor(ps[r], o);
      pd[r] += __shfl_xor(pd[r], o);
    }
  }
  int rowb = r0 + wv * 16 + quad * 4;
  if (m == 0) {
#pragma unroll
    for (int r = 0; r < 4; ++r) {
      int row = rowb + r;
      if (row < N_NODES) {
        a_s[2 * row + ch] = ps[r];
        a_d[2 * row + ch] = pd[r];
      }
    }
  }
  // xp store via LDS transpose -> coalesced uint4 stores (was 2B/lane scalar stores)
  __syncthreads();                   // all waves done reading B bufs
  unsigned short* st = (unsigned short*)smemI + wv * 2048;   // 16 rows x 128 cols
#pragma unroll
  for (int c = 0; c < 8; ++c)
#pragma unroll
    for (int r = 0; r < 4; ++r)
      st[(quad * 4 + r) * 128 + c * 16 + m] = f2bf(acc[c][r]);
  // wave-local: ds ordering guarantees visibility within the wave
#pragma unroll
  for (int p = 0; p < 4; ++p) {
    int rl = p * 4 + quad;
    uint4 vv = *(const uint4*)(st + rl * 128 + m * 8);
    int row = r0 + wv * 16 + rl;
    if (row < N_NODES)
      *(uint4*)(xp + (size_t)row * 256 + ch * 128 + m * 8) = vv;
  }
}

// ---------------- attention: one wave per dst node; 16 edges/iter (unchanged) ----------------
__global__ void attn_kernel(const unsigned short* __restrict__ xp,
                            const float* __restrict__ a_s, const float* __restrict__ a_d,
                            const int* __restrict__ offs, const int* __restrict__ csr,
                            const float* __restrict__ bias, unsigned short* __restrict__ y) {
  int nid = (blockIdx.x * 256 + (int)threadIdx.x) >> 6;
  int lane = threadIdx.x & 63;
  int l32 = lane & 31;
  int grp = lane >> 5;
  int h2 = l32 >> 4;
  float d0 = a_d[2 * nid], d1 = a_d[2 * nid + 1];
  float s0 = a_s[2 * nid], s1 = a_s[2 * nid + 1];
  int beg = offs[nid], end = offs[nid + 1];
  int deg = end - beg;
  float e0s = s0 + d0; e0s = e0s > 0.f ? e0s : 0.2f * e0s;
  float e1s = s1 + d1; e1s = e1s > 0.f ? e1s : 0.2f * e1s;

  if (deg <= 64) {
    int sreg = nid;
    float p0 = 0.f, p1 = 0.f;
    float e0 = -1e30f, e1 = -1e30f;
    if (lane < deg) {
      sreg = csr[beg + lane];
      float as0 = a_s[2 * sreg], as1 = a_s[2 * sreg + 1];
      e0 = as0 + d0; e0 = e0 > 0.f ? e0 : 0.2f * e0;
      e1 = as1 + d1; e1 = e1 > 0.f ? e1 : 0.2f * e1;
    }
    float m0 = fmaxf(e0, e0s), m1 = fmaxf(e1, e1s);
#pragma unroll
    for (int o = 32; o; o >>= 1) {
      m0 = fmaxf(m0, __shfl_xor(m0, o));
      m1 = fmaxf(m1, __shfl_xor(m1, o));
    }
    if (lane < deg) { p0 = __expf(e0 - m0); p1 = __expf(e1 - m1); }
    float ws0 = p0, ws1 = p1;
#pragma unroll
    for (int o = 32; o; o >>= 1) { ws0 += __shfl_xor(ws0, o); ws1 += __shfl_xor(ws1, o); }
    float wself0 = __expf(e0s - m0), wself1 = __expf(e1s - m1);
    float inv = 1.f / (h2 ? (ws1 + wself1) : (ws0 + wself0));

    float acc[8] = {0.f, 0.f, 0.f, 0.f, 0.f, 0.f, 0.f, 0.f};
    const unsigned* xpw = (const unsigned*)xp;
    {
      float wgt = grp ? 0.f : (h2 ? wself1 : wself0);
      uint4 u = *(const uint4*)(xpw + (size_t)nid * 128 + l32 * 4);
      acc[0] += wgt * bflo(u.x); acc[1] += wgt * bfhi(u.x);
      acc[2] += wgt * bflo(u.y); acc[3] += wgt * bfhi(u.y);
      acc[4] += wgt * bflo(u.z); acc[5] += wgt * bfhi(u.z);
      acc[6] += wgt * bflo(u.w); acc[7] += wgt * bfhi(u.w);
    }
    for (int j0 = 0; j0 < deg; j0 += 16) {
      int si[8]; float g[8];
#pragma unroll
      for (int i = 0; i < 8; ++i) {
        int e = j0 + 2 * i + grp;
        si[i] = __shfl(sreg, e);
        float a0 = __shfl(p0, e), a1 = __shfl(p1, e);
        g[i] = h2 ? a1 : a0;
      }
      uint4 u[8];
#pragma unroll
      for (int i = 0; i < 8; ++i)
        u[i] = *(const uint4*)(xpw + (size_t)si[i] * 128 + l32 * 4);
#pragma unroll
      for (int i = 0; i < 8; ++i) {
        acc[0] += g[i] * bflo(u[i].x); acc[1] += g[i] * bfhi(u[i].x);
        acc[2] += g[i] * bflo(u[i].y); acc[3] += g[i] * bfhi(u[i].y);
        acc[4] += g[i] * bflo(u[i].z); acc[5] += g[i] * bfhi(u[i].z);
        acc[6] += g[i] * bflo(u[i].w); acc[7] += g[i] * bfhi(u[i].w);
      }
    }
#pragma unroll
    for (int i = 0; i < 8; ++i) acc[i] += __shfl_xor(acc[i], 32);
    if (grp == 0) {
      int c0 = l32 * 8;
      float4 b0 = *(const float4*)(bias + c0);
      float4 b1 = *(const float4*)(bias + c0 + 4);
      float ob[8] = {b0.x, b0.y, b0.z, b0.w, b1.x, b1.y, b1.z, b1.w};
      unsigned short h[8];
#pragma unroll
      for (int i = 0; i < 8; ++i) {
        float v = acc[i] * inv + ob[i];
        v = v > 0.f ? v : __expf(v) - 1.f;
        h[i] = f2bf(v);
      }
      uint4 o;
      o.x = (unsigned)h[0] | ((unsigned)h[1] << 16);
      o.y = (unsigned)h[2] | ((unsigned)h[3] << 16);
      o.z = (unsigned)h[4] | ((unsigned)h[5] << 16);
      o.w = (unsigned)h[6] | ((unsigned)h[7] << 16);
      *(uint4*)(y + (size_t)nid * 256 + c0) = o;
    }
    return;
  }

  // slow path (deg > 64)
  int head = lane >> 5;
  float m0 = e0s, m1 = e1s;
  for (int j = beg + lane; j < end; j += 64) {
    int s = csr[j];
    float as0 = a_s[2 * s], as1 = a_s[2 * s + 1];
    float e0 = as0 + d0; e0 = e0 > 0.f ? e0 : 0.2f * e0;
    float e1 = as1 + d1; e1 = e1 > 0.f ? e1 : 0.2f * e1;
    m0 = fmaxf(m0, e0); m1 = fmaxf(m1, e1);
  }
#pragma unroll
  for (int o = 32; o; o >>= 1) {
    m0 = fmaxf(m0, __shfl_xor(m0, o));
    m1 = fmaxf(m1, __shfl_xor(m1, o));
  }
  float dh = head ? d1 : d0;
  float mh = head ? m1 : m0;
  float ax, ay, az, aw, wsum;
  {
    float e = head ? e1s : e0s;
    float wgt = __expf(e - mh);
    ushort4 u = *(const ushort4*)(xp + (size_t)nid * 256 + lane * 4);
    ax = wgt * bf2f(u.x); ay = wgt * bf2f(u.y); az = wgt * bf2f(u.z); aw = wgt * bf2f(u.w);
    wsum = wgt;
  }
  for (int j = beg; j < end; ++j) {
    int s = csr[j];
    float as = a_s[2 * s + head];
    float e = as + dh; e = e > 0.f ? e : 0.2f * e;
    float wgt = __expf(e - mh);
    ushort4 u = *(const ushort4*)(xp + (size_t)s * 256 + lane * 4);
    ax += wgt * bf2f(u.x); ay += wgt * bf2f(u.y); az += wgt * bf2f(u.z); aw += wgt * bf2f(u.w);
    wsum += wgt;
  }
  float inv = 1.f / wsum;
  float4 b4 = *(const float4*)(bias + lane * 4);
  float o0 = ax * inv + b4.x, o1 = ay * inv + b4.y;
  float o2 = az * inv + b4.z, o3 = aw * inv + b4.w;
  o0 = o0 > 0.f ? o0 : __expf(o0) - 1.f;
  o1 = o1 > 0.f ? o1 : __expf(o1) - 1.f;
  o2 = o2 > 0.f ? o2 : __expf(o2) - 1.f;
  o3 = o3 > 0.f ? o3 : __expf(o3) - 1.f;
  ushort4 yo; yo.x = f2bf(o0); yo.y = f2bf(o1); yo.z = f2bf(o2); yo.w = f2bf(o3);
  *(ushort4*)(y + (size_t)nid * 256 + lane * 4) = yo;
}

// ---------------- GEMM2: 938 blocks (64 rows x 64-col half), dbuf, A direct+prefetch ----------------
__global__ void __launch_bounds__(256) mlp_gemm_kernel(
    const unsigned short* __restrict__ y,
    const unsigned short* __restrict__ mwth, const unsigned short* __restrict__ mwtl,
    const float* __restrict__ mlp_b, const int* __restrict__ batch,
    float* __restrict__ S, float* __restrict__ Q) {
  __shared__ unsigned short Bh[2][2048], Bl[2][2048];   // 16 KB dbuf
  __shared__ float Sloc[64], Qloc[64];
  int tid = threadIdx.x;
  int w = tid >> 6, lane = tid & 63;
  int m = lane & 15, quad = lane >> 4;
  int rb = blockIdx.x >> 1, ch = blockIdx.x & 1;
  int r0 = rb * 64;
  if (tid < 64) { Sloc[tid] = 0.f; Qloc[tid] = 0.f; }
  const unsigned short* ap = y + (size_t)(r0 + w * 16 + m) * 256 + quad * 8;
  const unsigned short* bh = mwth + (size_t)(ch * 64) * 256;
  const unsigned short* bl = mwtl + (size_t)(ch * 64) * 256;

  f32x4 acc[4];
#pragma unroll
  for (int c = 0; c < 4; ++c) acc[c] = (f32x4){0.f, 0.f, 0.f, 0.f};

  bf16x8 a_cur = *(const bf16x8*)(ap);
  gld_lds16(bh + (size_t)lane * 256 + w * 8, &Bh[0][w * 512]);
  gld_lds16(bl + (size_t)lane * 256 + w * 8, &Bl[0][w * 512]);

  for (int kc = 0; kc < 8; ++kc) {
    const unsigned short* Bch = Bh[kc & 1];
    const unsigned short* Bcl = Bl[kc & 1];
    __syncthreads();
    bf16x8 a_nxt = a_cur;
    if (kc < 7) {
      int k0n = (kc + 1) * 32;
      gld_lds16(bh + (size_t)lane * 256 + k0n + w * 8, &Bh[(kc + 1) & 1][w * 512]);
      gld_lds16(bl + (size_t)lane * 256 + k0n + w * 8, &Bl[(kc + 1) & 1][w * 512]);
      a_nxt = *(const bf16x8*)(ap + k0n);
    }
#pragma unroll
    for (int c = 0; c < 4; ++c) {
      bf16x8 vh = *(const bf16x8*)(Bch + quad * 512 + (c * 16 + m) * 8);
      bf16x8 vl = *(const bf16x8*)(Bcl + quad * 512 + (c * 16 + m) * 8);
      acc[c] = __builtin_amdgcn_mfma_f32_16x16x32_bf16(a_cur, vh, acc[c], 0, 0, 0);
      acc[c] = __builtin_amdgcn_mfma_f32_16x16x32_bf16(a_cur, vl, acc[c], 0, 0, 0);
    }
    a_cur = a_nxt;
  }
  int rowb = r0 + w * 16 + quad * 4;
  int gfirst = batch[r0];
  int glast = batch[min(r0 + 63, N_NODES - 1)];
  bool uni = (gfirst == glast);
  bool valid[4]; int gg[4];
#pragma unroll
  for (int r = 0; r < 4; ++r) {
    int row = rowb + r;
    valid[r] = row < N_NODES;
    gg[r] = (!uni && valid[r]) ? batch[row] : gfirst;
  }
#pragma unroll
  for (int c = 0; c < 4; ++c) {
    int cl = c * 16 + m;
    int col = ch * 64 + cl;
    float bv = mlp_b[col];
    float sc = 0.f, qc = 0.f;
#pragma unroll
    for (int r = 0; r < 4; ++r) {
      if (valid[r]) {
        float v = acc[c][r] + bv;
        qc += v * v;
        if (uni) sc += v;
        else atomicAdd(&S[gg[r] * 128 + col], v);
      }
    }
    qc += __shfl_xor(qc, 16); qc += __shfl_xor(qc, 32);
    sc += __shfl_xor(sc, 16); sc += __shfl_xor(sc, 32);
    if (quad == 0) {
      atomicAdd(&Qloc[cl], qc);
      if (uni) atomicAdd(&Sloc[cl], sc);
    }
  }
  __syncthreads();
  if (tid < 64) {
    atomicAdd(&Q[ch * 64 + tid], Qloc[tid]);
    if (uni) atomicAdd(&S[gfirst * 128 + ch * 64 + tid], Sloc[tid]);
  }
}

// ---------------- FC head ----------------
__global__ void fc1_kernel(const float* __restrict__ S, const float* __restrict__ Q,
                           const int* __restrict__ cnt, const float* __restrict__ g0,
                           const float* __restrict__ b0,
                           const float* __restrict__ w, const float* __restrict__ b,
                           const float* __restrict__ bng, const float* __restrict__ bnb,
                           float* __restrict__ z1t) {
  __shared__ float hp[64 * 129];
  int tid = threadIdx.x;
  if (tid < 128) {
    int c = tid;
    float sum = 0.f;
    for (int g = 0; g < NGRAPH; ++g) sum += S[g * 128 + c];
    float mu = sum / (float)N_NODES;
    float var = Q[c] / (float)N_NODES - mu * mu;
    float gam = g0[c] * rsqrtf(var + BN_EPS);
    float bet = b0[c];
    for (int g = 0; g < NGRAPH; ++g) {
      float k = (float)cnt[g];
      hp[g * 129 + c] = gam * (S[g * 128 + c] - k * mu) + k * bet;
    }
  }
  __syncthreads();
  int wv = tid >> 6, lane = tid & 63;
  int j = blockIdx.x * 4 + wv;
  float acc = b[j];
  for (int c = 0; c < 128; ++c) acc += hp[lane * 129 + c] * w[c * 512 + j];
  float s1 = acc, s2 = acc * acc;
#pragma unroll
  for (int o = 32; o; o >>= 1) { s1 += __shfl_xor(s1, o); s2 += __shfl_xor(s2, o); }
  float mu = s1 * (1.f / 64.f), var = s2 * (1.f / 64.f) - mu * mu;
  float z = bng[j] * (acc - mu) * rsqrtf(var + BN_EPS) + bnb[j];
  z1t[j * 64 + lane] = fmaxf(z, 0.f);
}

__global__ void fc2_kernel(const float* __restrict__ z1t, const float* __restrict__ w,
                           const float* __restrict__ b, const float* __restrict__ bng,
                           const float* __restrict__ bnb, float* __restrict__ z2t) {
  int wv = threadIdx.x >> 6, lane = threadIdx.x & 63;
  int j = blockIdx.x * 4 + wv;
  float acc = b[j];
  for (int c = 0; c < 512; ++c) acc += z1t[c * 64 + lane] * w[c * 256 + j];
  float s1 = acc, s2 = acc * acc;
#pragma unroll
  for (int o = 32; o; o >>= 1) { s1 += __shfl_xor(s1, o); s2 += __shfl_xor(s2, o); }
  float mu = s1 * (1.f / 64.f), var = s2 * (1.f / 64.f) - mu * mu;
  float z = bng[j] * (acc - mu) * rsqrtf(var + BN_EPS) + bnb[j];
  z2t[j * 64 + lane] = fmaxf(z, 0.f);
}

__global__ void fc3_kernel(const float* __restrict__ z2t, const float* __restrict__ w,
                           const float* __restrict__ b, const float* __restrict__ bng,
                           const float* __restrict__ bnb, float* __restrict__ out) {
  int lane = threadIdx.x;
  float acc = b[0];
  for (int c = 0; c < 256; ++c) acc += z2t[c * 64 + lane] * w[c];
  float s1 = acc, s2 = acc * acc;
#pragma unroll
  for (int o = 32; o; o >>= 1) { s1 += __shfl_xor(s1, o); s2 += __shfl_xor(s2, o); }
  float mu = s1 * (1.f / 64.f), var = s2 * (1.f / 64.f) - mu * mu;
  out[lane] = bng[0] * (acc - mu) * rsqrtf(var + BN_EPS) + bnb[0];
}

extern "C" void kernel_launch(void* const* d_in, const int* in_sizes, int n_in,
                              void* d_out, int out_size, void* d_ws, size_t ws_size,
                              hipStream_t stream) {
  const float* x     = (const float*)d_in[0];
  const float* gat_w = (const float*)d_in[1];
  const float* a_src = (const float*)d_in[2];
  const float* a_dst = (const float*)d_in[3];
  const float* gbias = (const float*)d_in[4];
  const float* mlp_w = (const float*)d_in[5];
  const float* mlp_b = (const float*)d_in[6];
  const float* bn0g  = (const float*)d_in[7];
  const float* bn0b  = (const float*)d_in[8];
  const float* fc1w  = (const float*)d_in[9];
  const float* fc1b  = (const float*)d_in[10];
  const float* bn1g  = (const float*)d_in[11];
  const float* bn1b  = (const float*)d_in[12];
  const float* fc2w  = (const float*)d_in[13];
  const float* fc2b  = (const float*)d_in[14];
  const float* bn2g  = (const float*)d_in[15];
  const float* bn2b  = (const float*)d_in[16];
  const float* fc3w  = (const float*)d_in[17];
  const float* fc3b  = (const float*)d_in[18];
  const float* bn3g  = (const float*)d_in[19];
  const float* bn3b  = (const float*)d_in[20];
  const int* eidx    = (const int*)d_in[21];
  const int* batch   = (const int*)d_in[22];
  float* out = (float*)d_out;

  char* base = (char*)d_ws;
  size_t off = 0;
  auto take = [&](size_t bytes) -> char* {
    char* p = base + off;
    off += (bytes + 255) & ~(size_t)255;
    return p;
  };
  unsigned short* xp   = (unsigned short*)take((size_t)N_NODES * 256 * 2);
  unsigned short* ybf  = (unsigned short*)take((size_t)30016 * 256 * 2);
  unsigned short* wth  = (unsigned short*)take(448 * 256 * 2);
  unsigned short* mwth = (unsigned short*)take(128 * 256 * 2);
  unsigned short* mwtl = (unsigned short*)take(128 * 256 * 2);
  float* a_s = (float*)take((size_t)N_NODES * 2 * 4);
  float* a_d = (float*)take((size_t)N_NODES * 2 * 4);
  int* offs  = (int*)take((size_t)(N_NODES + 1) * 4);
  int* csr   = (int*)take((size_t)N_EDGES * 4);
  int2* binbuf = (int2*)take((size_t)NBUCKET * BCAP * 8);
  int* gcur  = (int*)take((size_t)NBUCKET * GC_STRIDE * 4);
  float* S   = (float*)take(NGRAPH * 128 * 4);
  float* Q   = (float*)take(128 * 4);
  int* cnt   = (int*)take(NGRAPH * 4);
  float* z1t = (float*)take(512 * 64 * 4);
  float* z2t = (float*)take(256 * 64 * 4);

  hipMemsetAsync(gcur, 0, (size_t)NBUCKET * GC_STRIDE * 4, stream);
  hipMemsetAsync(S, 0, (size_t)(NGRAPH * 128 * 4 + 512), stream);

  prep_kernel<<<975, 256, 0, stream>>>(eidx, binbuf, gcur, gat_w, mlp_w,
                                       wth, mwth, mwtl, batch, cnt);
  gat_build_kernel<<<BLD_N + 938, 256, 0, stream>>>(binbuf, gcur, offs, csr,
                                                    x, wth, a_src, a_dst, xp, a_s, a_d);
  attn_kernel<<<7500, 256, 0, stream>>>(xp, a_s, a_d, offs, csr, gbias, ybf);
  mlp_gemm_kernel<<<938, 256, 0, stream>>>(ybf, mwth, mwtl, mlp_b, batch, S, Q);
  fc1_kernel<<<128, 256, 0, stream>>>(S, Q, cnt, bn0g, bn0b, fc1w, fc1b, bn1g, bn1b, z1t);
  fc2_kernel<<<64, 256, 0, stream>>>(z1t, fc2w, fc2b, bn2g, bn2b, z2t);
  fc3_kernel<<<1, 64, 0, stream>>>(z2t, fc3w, fc3b, bn3g, bn3b, out);

  (void)in_sizes; (void)n_in; (void)out_size; (void)ws_size;
}